// Round 1
// baseline (70.006 us; speedup 1.0000x reference)
//
#include <hip/hip_runtime.h>

#define NSAMP 64
#define PER_SAMPLE (512 * 512)          // 262144 elements per sample
#define BLOCKS_PER_SAMPLE 16
#define THREADS 256
#define TOPK 42
#define LOG_CLAMP -100.0f

// Kernel 1: per-block partial BCE sums.
// grid = NSAMP * BLOCKS_PER_SAMPLE blocks of THREADS.
// Each block owns a contiguous chunk of one sample; writes ONE partial sum
// to ws[blockIdx.x]. No atomics -> deterministic.
__global__ __launch_bounds__(THREADS) void bce_partial(
    const float* __restrict__ preds,
    const float* __restrict__ targets,
    float* __restrict__ partials) {
    const int vec_per_sample = PER_SAMPLE / 4;                    // 65536 float4
    const int vec_per_block  = vec_per_sample / BLOCKS_PER_SAMPLE; // 4096 float4
    const int sample = blockIdx.x / BLOCKS_PER_SAMPLE;
    const int chunk  = blockIdx.x % BLOCKS_PER_SAMPLE;
    const size_t base = (size_t)sample * vec_per_sample + (size_t)chunk * vec_per_block;

    const float4* __restrict__ p4 = (const float4*)preds;
    const float4* __restrict__ t4 = (const float4*)targets;

    float acc = 0.0f;
    for (int i = threadIdx.x; i < vec_per_block; i += THREADS) {
        float4 p = p4[base + i];
        float4 t = t4[base + i];
        {
            float lp  = fmaxf(logf(p.x),    LOG_CLAMP);
            float l1  = fmaxf(log1pf(-p.x), LOG_CLAMP);
            acc -= t.x * lp + (1.0f - t.x) * l1;
        }
        {
            float lp  = fmaxf(logf(p.y),    LOG_CLAMP);
            float l1  = fmaxf(log1pf(-p.y), LOG_CLAMP);
            acc -= t.y * lp + (1.0f - t.y) * l1;
        }
        {
            float lp  = fmaxf(logf(p.z),    LOG_CLAMP);
            float l1  = fmaxf(log1pf(-p.z), LOG_CLAMP);
            acc -= t.z * lp + (1.0f - t.z) * l1;
        }
        {
            float lp  = fmaxf(logf(p.w),    LOG_CLAMP);
            float l1  = fmaxf(log1pf(-p.w), LOG_CLAMP);
            acc -= t.w * lp + (1.0f - t.w) * l1;
        }
    }

    // wave (64-lane) reduction
    #pragma unroll
    for (int off = 32; off > 0; off >>= 1) acc += __shfl_down(acc, off, 64);

    __shared__ float smem[THREADS / 64];
    const int lane = threadIdx.x & 63;
    const int wid  = threadIdx.x >> 6;
    if (lane == 0) smem[wid] = acc;
    __syncthreads();
    if (threadIdx.x == 0) {
        float tot = 0.0f;
        #pragma unroll
        for (int w = 0; w < THREADS / 64; ++w) tot += smem[w];
        partials[blockIdx.x] = tot;
    }
}

// Kernel 2: one block, 64 threads (one wave). Reduce partials -> per-sample
// mean loss; stable O(64^2) rank to select the 42 largest; mean of those.
__global__ __launch_bounds__(64) void topk_mean(
    const float* __restrict__ partials,
    float* __restrict__ out) {
    const int tid = threadIdx.x;  // 0..63, one sample each
    float s = 0.0f;
    #pragma unroll
    for (int c = 0; c < BLOCKS_PER_SAMPLE; ++c)
        s += partials[tid * BLOCKS_PER_SAMPLE + c];
    const float loss = s * (1.0f / (float)PER_SAMPLE);

    __shared__ float vals[NSAMP];
    vals[tid] = loss;
    __syncthreads();

    // Descending stable rank: count strictly-greater values, plus equal
    // values at lower index. Exactly TOPK entries get rank < TOPK.
    int rank = 0;
    for (int j = 0; j < NSAMP; ++j) {
        float v = vals[j];
        rank += (v > loss) || (v == loss && j < tid);
    }
    float contrib = (rank < TOPK) ? loss : 0.0f;

    #pragma unroll
    for (int off = 32; off > 0; off >>= 1) contrib += __shfl_down(contrib, off, 64);

    if (tid == 0) out[0] = contrib * (1.0f / (float)TOPK);
}

extern "C" void kernel_launch(void* const* d_in, const int* in_sizes, int n_in,
                              void* d_out, int out_size, void* d_ws, size_t ws_size,
                              hipStream_t stream) {
    const float* preds   = (const float*)d_in[0];
    const float* targets = (const float*)d_in[1];
    float* out      = (float*)d_out;
    float* partials = (float*)d_ws;   // NSAMP*BLOCKS_PER_SAMPLE floats = 4 KB

    bce_partial<<<NSAMP * BLOCKS_PER_SAMPLE, THREADS, 0, stream>>>(preds, targets, partials);
    topk_mean<<<1, 64, 0, stream>>>(partials, out);
}

// Round 2
// 28.797 us; speedup vs baseline: 2.4310x; 2.4310x over previous
//
#include <hip/hip_runtime.h>

#define NSAMP 64
#define PER_SAMPLE (512 * 512)            // 262144 elements per sample
#define BLOCKS_PER_SAMPLE 64
#define NBLOCKS (NSAMP * BLOCKS_PER_SAMPLE)   // 4096 blocks
#define THREADS 256
#define TOPK 42
#define LOG_CLAMP -100.0f

// Kernel 1: per-block partial BCE sums, hardware-log fast path.
// Each block owns a contiguous 4096-element chunk of one sample (1024 float4,
// 4 fully-unrolled iterations per thread). One deterministic partial per
// block -> ws[blockIdx.x]. No atomics.
__global__ __launch_bounds__(THREADS) void bce_partial(
    const float* __restrict__ preds,
    const float* __restrict__ targets,
    float* __restrict__ partials) {
    const int vec_per_sample = PER_SAMPLE / 4;                      // 65536
    const int vec_per_block  = vec_per_sample / BLOCKS_PER_SAMPLE;  // 1024
    const int sample = blockIdx.x / BLOCKS_PER_SAMPLE;
    const int chunk  = blockIdx.x % BLOCKS_PER_SAMPLE;
    const size_t base = (size_t)sample * vec_per_sample + (size_t)chunk * vec_per_block;

    const float4* __restrict__ p4 = (const float4*)preds;
    const float4* __restrict__ t4 = (const float4*)targets;

    float acc = 0.0f;   // accumulates +(l1 + t*(lp-l1)); negated at the end
    #pragma unroll
    for (int it = 0; it < vec_per_block / THREADS; ++it) {
        const int i = it * THREADS + threadIdx.x;
        float4 p = p4[base + i];
        float4 t = t4[base + i];

        // per lane-element: lp = max(log p, -100), l1 = max(log(1-p), -100)
        // contribution = l1 + t*(lp - l1)
        {
            float lp = fmaxf(__logf(p.x),        LOG_CLAMP);
            float l1 = fmaxf(__logf(1.0f - p.x), LOG_CLAMP);
            acc += l1;  acc = fmaf(t.x, lp - l1, acc);
        }
        {
            float lp = fmaxf(__logf(p.y),        LOG_CLAMP);
            float l1 = fmaxf(__logf(1.0f - p.y), LOG_CLAMP);
            acc += l1;  acc = fmaf(t.y, lp - l1, acc);
        }
        {
            float lp = fmaxf(__logf(p.z),        LOG_CLAMP);
            float l1 = fmaxf(__logf(1.0f - p.z), LOG_CLAMP);
            acc += l1;  acc = fmaf(t.z, lp - l1, acc);
        }
        {
            float lp = fmaxf(__logf(p.w),        LOG_CLAMP);
            float l1 = fmaxf(__logf(1.0f - p.w), LOG_CLAMP);
            acc += l1;  acc = fmaf(t.w, lp - l1, acc);
        }
    }

    // wave (64-lane) butterfly reduction
    #pragma unroll
    for (int off = 32; off > 0; off >>= 1) acc += __shfl_down(acc, off, 64);

    __shared__ float smem[THREADS / 64];
    const int lane = threadIdx.x & 63;
    const int wid  = threadIdx.x >> 6;
    if (lane == 0) smem[wid] = acc;
    __syncthreads();
    if (threadIdx.x == 0) {
        float tot = 0.0f;
        #pragma unroll
        for (int w = 0; w < THREADS / 64; ++w) tot += smem[w];
        partials[blockIdx.x] = -tot;   // negate once per block
    }
}

// Kernel 2: one 64-thread block. Per-sample mean loss; stable O(64^2) rank
// to pick the 42 largest; mean of those.
__global__ __launch_bounds__(64) void topk_mean(
    const float* __restrict__ partials,
    float* __restrict__ out) {
    const int tid = threadIdx.x;  // one sample per thread
    float s = 0.0f;
    #pragma unroll
    for (int c = 0; c < BLOCKS_PER_SAMPLE; ++c)
        s += partials[tid * BLOCKS_PER_SAMPLE + c];
    const float loss = s * (1.0f / (float)PER_SAMPLE);

    __shared__ float vals[NSAMP];
    vals[tid] = loss;
    __syncthreads();

    // Descending stable rank: exactly TOPK entries get rank < TOPK.
    int rank = 0;
    for (int j = 0; j < NSAMP; ++j) {
        float v = vals[j];
        rank += (v > loss) || (v == loss && j < tid);
    }
    float contrib = (rank < TOPK) ? loss : 0.0f;

    #pragma unroll
    for (int off = 32; off > 0; off >>= 1) contrib += __shfl_down(contrib, off, 64);

    if (tid == 0) out[0] = contrib * (1.0f / (float)TOPK);
}

extern "C" void kernel_launch(void* const* d_in, const int* in_sizes, int n_in,
                              void* d_out, int out_size, void* d_ws, size_t ws_size,
                              hipStream_t stream) {
    const float* preds   = (const float*)d_in[0];
    const float* targets = (const float*)d_in[1];
    float* out      = (float*)d_out;
    float* partials = (float*)d_ws;   // NBLOCKS floats = 16 KB

    bce_partial<<<NBLOCKS, THREADS, 0, stream>>>(preds, targets, partials);
    topk_mean<<<1, 64, 0, stream>>>(partials, out);
}

// Round 3
// 27.021 us; speedup vs baseline: 2.5908x; 1.0657x over previous
//
#include <hip/hip_runtime.h>

#define NSAMP 64
#define PER_SAMPLE (512 * 512)                 // 262144 elements per sample
#define BLOCKS_PER_SAMPLE 32
#define NBLOCKS (NSAMP * BLOCKS_PER_SAMPLE)    // 2048 blocks
#define THREADS 256
#define TOPK 42
#define LOG2_CLAMP -144.26950408889634f        // -100 / ln(2)
#define LN2F 0.69314718055994531f

// Kernel 1: per-block partial BCE sums in log2 domain.
// Each block owns a contiguous 8192-element chunk of one sample (2048 float4).
// Per thread: 8 float4-pairs in 2 batches of 4 (8 loads in flight per batch).
// One deterministic partial per block -> ws[blockIdx.x]. No atomics.
__global__ __launch_bounds__(THREADS) void bce_partial(
    const float* __restrict__ preds,
    const float* __restrict__ targets,
    float* __restrict__ partials) {
    const int vec_per_sample = PER_SAMPLE / 4;                      // 65536
    const int vec_per_block  = vec_per_sample / BLOCKS_PER_SAMPLE;  // 2048
    const int sample = blockIdx.x >> 5;          // /32
    const int chunk  = blockIdx.x & 31;          // %32
    const size_t base = (size_t)sample * vec_per_sample + (size_t)chunk * vec_per_block;

    const float4* __restrict__ p4 = (const float4*)preds;
    const float4* __restrict__ t4 = (const float4*)targets;

    // acc holds +(t*log2(p) + (1-t)*log2(1-p)); negate & scale by ln2 at end.
    float acc = 0.0f;
    #pragma unroll
    for (int b = 0; b < 2; ++b) {
        float4 p[4], t[4];
        #pragma unroll
        for (int j = 0; j < 4; ++j) {
            const int i = (b * 4 + j) * THREADS + threadIdx.x;
            p[j] = p4[base + i];
            t[j] = t4[base + i];
        }
        #pragma unroll
        for (int j = 0; j < 4; ++j) {
            {
                float lp = fmaxf(__log2f(p[j].x),        LOG2_CLAMP);
                float l1 = fmaxf(__log2f(1.0f - p[j].x), LOG2_CLAMP);
                acc += l1;  acc = fmaf(t[j].x, lp - l1, acc);
            }
            {
                float lp = fmaxf(__log2f(p[j].y),        LOG2_CLAMP);
                float l1 = fmaxf(__log2f(1.0f - p[j].y), LOG2_CLAMP);
                acc += l1;  acc = fmaf(t[j].y, lp - l1, acc);
            }
            {
                float lp = fmaxf(__log2f(p[j].z),        LOG2_CLAMP);
                float l1 = fmaxf(__log2f(1.0f - p[j].z), LOG2_CLAMP);
                acc += l1;  acc = fmaf(t[j].z, lp - l1, acc);
            }
            {
                float lp = fmaxf(__log2f(p[j].w),        LOG2_CLAMP);
                float l1 = fmaxf(__log2f(1.0f - p[j].w), LOG2_CLAMP);
                acc += l1;  acc = fmaf(t[j].w, lp - l1, acc);
            }
        }
    }

    // wave (64-lane) butterfly reduction
    #pragma unroll
    for (int off = 32; off > 0; off >>= 1) acc += __shfl_down(acc, off, 64);

    __shared__ float smem[THREADS / 64];
    const int lane = threadIdx.x & 63;
    const int wid  = threadIdx.x >> 6;
    if (lane == 0) smem[wid] = acc;
    __syncthreads();
    if (threadIdx.x == 0) {
        float tot = 0.0f;
        #pragma unroll
        for (int w = 0; w < THREADS / 64; ++w) tot += smem[w];
        partials[blockIdx.x] = -tot * LN2F;   // back to natural-log domain
    }
}

// Kernel 2: one 64-thread block. Vectorized gather of 32 partials/sample,
// per-sample mean; stable O(64^2) rank to pick the 42 largest; mean.
__global__ __launch_bounds__(64) void topk_mean(
    const float* __restrict__ partials,
    float* __restrict__ out) {
    const int tid = threadIdx.x;  // one sample per thread
    const float4* __restrict__ pp4 = (const float4*)partials;

    float4 a[8];
    #pragma unroll
    for (int j = 0; j < 8; ++j) a[j] = pp4[tid * 8 + j];   // 32 floats/sample
    float s = 0.0f;
    #pragma unroll
    for (int j = 0; j < 8; ++j) s += a[j].x + a[j].y + a[j].z + a[j].w;
    const float loss = s * (1.0f / (float)PER_SAMPLE);

    __shared__ float vals[NSAMP];
    vals[tid] = loss;
    __syncthreads();

    // Descending stable rank: exactly TOPK entries get rank < TOPK.
    int rank = 0;
    for (int j = 0; j < NSAMP; ++j) {
        float v = vals[j];
        rank += (v > loss) || (v == loss && j < tid);
    }
    float contrib = (rank < TOPK) ? loss : 0.0f;

    #pragma unroll
    for (int off = 32; off > 0; off >>= 1) contrib += __shfl_down(contrib, off, 64);

    if (tid == 0) out[0] = contrib * (1.0f / (float)TOPK);
}

extern "C" void kernel_launch(void* const* d_in, const int* in_sizes, int n_in,
                              void* d_out, int out_size, void* d_ws, size_t ws_size,
                              hipStream_t stream) {
    const float* preds   = (const float*)d_in[0];
    const float* targets = (const float*)d_in[1];
    float* out      = (float*)d_out;
    float* partials = (float*)d_ws;   // NBLOCKS floats = 8 KB

    bce_partial<<<NBLOCKS, THREADS, 0, stream>>>(preds, targets, partials);
    topk_mean<<<1, 64, 0, stream>>>(partials, out);
}